// Round 8
// baseline (177.298 us; speedup 1.0000x reference)
//
#include <hip/hip_runtime.h>

// CASREL loss, B=32,S=512,H=1024,R=64 -> scalar fp32 loss.
// v9: barrier-free main loop. Root cause of the 41.5us plateau (v1-v8):
// every chunk's "prefetch" loads were drained by the vmcnt(0) implicit in
// __syncthreads right after issue -> zero overlap, lockstep bursts.
// Fix: column-split. Block = 128 rows x 80 cols x full K. B-slice (80x1024
// bf16 = exactly 160KB) staged to LDS ONCE (gload_lds + 1 barrier), then a
// barrier-free K-stream: each wave reads its own A fragments directly from
// global (coalesced 128B/row), cvt in-reg, MFMA vs LDS B (XOR-swz, verified).
// Twin blocks (bid^1) share A rows -> 2nd read L3-hits. Reduce: wave shfl ->
// per-block ws slot -> 1 atomic/block. aux_kernel unchanged.

#define B_  32
#define S_  512
#define H_  1024
#define R_  64
#define M_  (B_ * S_)      // 16384 rows
#define NPAD 160           // 130 valid cols padded
#define NVALID 130
#define MT 128             // rows per block
#define CGC 80             // cols per block (2 col-groups)
#define TBLK 20            // transpose blocks (5 n-tiles x 4 k-tiles)
#define NTHR 512           // 8 waves
#define NKS (H_ / 32)      // 32 k-steps

typedef __attribute__((ext_vector_type(4))) float  floatx4;
typedef __attribute__((ext_vector_type(8))) short  short8;     // 8 bf16
typedef __attribute__((ext_vector_type(8))) unsigned short u16x8;

__device__ __forceinline__ unsigned short f2bf(float f) {
    unsigned int u = __float_as_uint(f);
    u = (u + 0x7FFFu + ((u >> 16) & 1u)) >> 16;   // RNE
    return (unsigned short)u;
}

__device__ __forceinline__ short8 cvt8(float4 a, float4 b) {
    union { unsigned short us[8]; short8 s8; } u;
    u.us[0] = f2bf(a.x); u.us[1] = f2bf(a.y); u.us[2] = f2bf(a.z); u.us[3] = f2bf(a.w);
    u.us[4] = f2bf(b.x); u.us[5] = f2bf(b.y); u.us[6] = f2bf(b.z); u.us[7] = f2bf(b.w);
    return u.s8;
}

__device__ __forceinline__ void gload16(const void* g, void* l) {
    __builtin_amdgcn_global_load_lds(
        (const __attribute__((address_space(1))) unsigned int*)g,
        (__attribute__((address_space(3))) unsigned int*)l, 16, 0, 0);
}

// ---- K1 (merged): blocks [0,TBLK) transpose WtG; blocks [TBLK,TBLK+B_) subj ----
__global__ __launch_bounds__(256) void aux_kernel(
        const float* __restrict__ ctx, const float* __restrict__ head,
        const float* __restrict__ tail, const float* __restrict__ masks,
        const float* __restrict__ Wo_h, const float* __restrict__ Wo_t,
        const float* __restrict__ Ws_h, const float* __restrict__ Ws_t,
        const float* __restrict__ bo_h, const float* __restrict__ bo_t,
        const float* __restrict__ bs_h, const float* __restrict__ bs_t,
        unsigned short* __restrict__ WtG, float* __restrict__ rowBias,
        float* __restrict__ accum) {
    const int tid = threadIdx.x;
    __shared__ float tr[32][257];      // transpose tile (pad 257: conflict-free)
    __shared__ float subj[H_];
    __shared__ float partS[4][256];
    __shared__ int cnt;
    __shared__ int   sidx[8];
    __shared__ float sw[8];

    if (blockIdx.x < TBLK) {
        const int kt = blockIdx.x / 5, nt = blockIdx.x % 5;
        const int k0 = kt * 256, n0 = nt * 32;
        if (n0 < 128) {
            const float* src = (n0 < 64) ? Wo_h : Wo_t;
            const int cb = n0 & 63;
            const int nn = tid & 31, kk = tid >> 5;   // 8 k-rows per pass
#pragma unroll
            for (int i = 0; i < 32; ++i) {
                const int k = k0 + i * 8 + kk;
                tr[nn][i * 8 + kk] = src[(size_t)k * R_ + cb + nn];
            }
            __syncthreads();
#pragma unroll
            for (int p = 0; p < 4; ++p) {
                const int chunk = p * 256 + tid;
                const int n = chunk >> 5;             // 0..31
                const int kc = (chunk & 31) * 8;
                u16x8 v;
#pragma unroll
                for (int j = 0; j < 8; ++j) v[j] = f2bf(tr[n][kc + j]);
                *(u16x8*)(WtG + (size_t)(n0 + n) * H_ + k0 + kc) = v;
            }
        } else {
#pragma unroll
            for (int p = 0; p < 4; ++p) {
                const int chunk = p * 256 + tid;
                const int n = 128 + (chunk >> 5);
                const int kc = (chunk & 31) * 8;
                u16x8 v;
#pragma unroll
                for (int j = 0; j < 8; ++j) {
                    float f = (n == 128) ? Ws_h[k0 + kc + j]
                            : (n == 129) ? Ws_t[k0 + kc + j] : 0.0f;
                    v[j] = f2bf(f);
                }
                *(u16x8*)(WtG + (size_t)n * H_ + k0 + kc) = v;
            }
        }
        return;
    }

    const int b = blockIdx.x - TBLK;
    if (tid == 0) cnt = 0;
    __syncthreads();
    float msk = 0.0f;
    for (int s = tid; s < S_; s += 256) {
        float w = 0.5f * (head[b * S_ + s] + tail[b * S_ + s]);
        if (w != 0.0f) {
            int i = atomicAdd(&cnt, 1);
            if (i < 8) { sidx[i] = s; sw[i] = w; }
        }
        msk += masks[b * S_ + s];
    }
    for (int o = 32; o > 0; o >>= 1) msk += __shfl_down(msk, o, 64);
    if ((tid & 63) == 0) atomicAdd(&accum[1], msk);
    __syncthreads();
    const int nnz = cnt < 8 ? cnt : 8;
    for (int h = tid; h < H_; h += 256) {
        float a = 0.0f;
        for (int i = 0; i < nnz; i++)
            a += sw[i] * ctx[((size_t)b * S_ + sidx[i]) * H_ + h];
        subj[h] = a;
    }
    __syncthreads();
    {   // rowBias dot: thread = (c-group of 4, k-slice of 128); float4 W loads
        const int cg = tid & 31;
        const int ks = tid >> 5;
        const int c4 = cg * 4;
        const float* W = (c4 < 64) ? Wo_h : Wo_t;
        const int cc = c4 & 63;
        const int kk0 = ks * 128;
        float ax = 0.f, ay = 0.f, az = 0.f, aw2 = 0.f;
#pragma unroll 4
        for (int k = kk0; k < kk0 + 128; ++k) {
            const float4 w = *(const float4*)(W + (size_t)k * R_ + cc);
            const float sv = subj[k];
            ax += sv * w.x; ay += sv * w.y; az += sv * w.z; aw2 += sv * w.w;
        }
        partS[0][tid] = ax; partS[1][tid] = ay;
        partS[2][tid] = az; partS[3][tid] = aw2;
    }
    __syncthreads();
    if (tid < NPAD) {
        float bias = tid < 64  ? bo_h[tid]
                   : tid < 128 ? bo_t[tid - 64]
                   : tid == 128 ? bs_h[0]
                   : tid == 129 ? bs_t[0] : 0.0f;
        float a2 = 0.0f;
        if (tid < 128) {
            const int g = tid >> 2, j = tid & 3;
#pragma unroll
            for (int s = 0; s < 8; ++s) a2 += partS[j][s * 32 + g];
        }
        rowBias[b * NPAD + tid] = bias + a2;
    }
}

// ---- K2: col-split, barrier-free streaming GEMM + BCE + reduce + finalize ----
__global__ __launch_bounds__(NTHR) void main_kernel(
        const float* __restrict__ ctx, const unsigned short* __restrict__ WtG,
        const float* __restrict__ rowBias, const float* __restrict__ masks,
        const float* __restrict__ ash, const float* __restrict__ ast,
        const float* __restrict__ oh, const float* __restrict__ ot,
        float* __restrict__ accum, float* __restrict__ accumB,
        float* __restrict__ out) {
    __shared__ __align__(16) unsigned short Bsm[CGC * H_];   // 163840 B = full LDS

    const int tid  = threadIdx.x;
    const int bid  = blockIdx.x;
    const int mb   = bid >> 1, cg = bid & 1;     // twins share rows -> L3 reuse
    const int gm0  = mb * MT;
    const int b    = gm0 >> 9;
    const int wave = tid >> 6, lane = tid & 63;
    const int lr = lane & 15, q = lane >> 4;     // q in 0..3
    const int col0 = cg * CGC;

    // ---- stage B once: 160KB, linear LDS dest, XOR-swizzled global source ----
#pragma unroll
    for (int p = 0; p < (CGC * H_ * 2 / 16) / NTHR; ++p) {   // 20 passes
        const int i = p * NTHR + tid;            // 16B chunk index
        const int row = i >> 7;                  // local col 0..79
        const int bytecol = (i & 127) << 4;      // 0..2032
        const int srcb = bytecol ^ ((row & 7) << 4);
        gload16((const char*)(WtG + (size_t)(col0 + row) * H_) + srcb,
                (char*)Bsm + i * 16);
    }
    __syncthreads();   // one-time drain: B resident for the whole kernel

    // ---- barrier-free K-stream ----
    const int arow = gm0 + wave * 16 + lr;       // each wave owns 16 rows
    const float* aP = ctx + (size_t)arow * H_ + q * 8;
    const int swz = (lr & 7) << 4;
    const int oe = (q << 4) ^ swz;               // kk even byte offset in 128B
    const int oo = (64 | (q << 4)) ^ swz;        // kk odd
    int rb5[5];
#pragma unroll
    for (int t = 0; t < 5; ++t) rb5[t] = (t * 16 + lr) * 2048;

    floatx4 acc[5];
#pragma unroll
    for (int t = 0; t < 5; ++t) acc[t] = (floatx4){0.f, 0.f, 0.f, 0.f};

#pragma unroll
    for (int kk = 0; kk < NKS; ++kk) {
        const float4 f0 = *(const float4*)(aP + kk * 32);
        const float4 f1 = *(const float4*)(aP + kk * 32 + 4);
        const short8 afr = cvt8(f0, f1);
        const int kb = (kk >> 1) * 128 + ((kk & 1) ? oo : oe);
#pragma unroll
        for (int t = 0; t < 5; ++t) {
            const short8 bfr = *(const short8*)((const char*)Bsm + rb5[t] + kb);
            acc[t] = __builtin_amdgcn_mfma_f32_16x16x32_bf16(afr, bfr, acc[t], 0, 0, 0);
        }
    }

    // ---- epilogue: logits -> BCE * mask -> sum ----
    float lsum = 0.0f;
#pragma unroll
    for (int t = 0; t < 5; ++t) {
        const int col = col0 + t * 16 + lr;
        if (col < NVALID) {
            const float rbv = rowBias[b * NPAD + col];
#pragma unroll
            for (int i = 0; i < 4; ++i) {
                const int row = gm0 + wave * 16 + q * 4 + i;
                const float l = acc[t][i] + rbv;
                float tgt;
                if (col < 64)        tgt = oh[(size_t)row * R_ + col];
                else if (col < 128)  tgt = ot[(size_t)row * R_ + (col - 64)];
                else if (col == 128) tgt = ash[row];
                else                 tgt = ast[row];
                const float mk = masks[row];
                const float bce = fmaxf(l, 0.0f) - l * tgt + log1pf(__expf(-fabsf(l)));
                lsum += bce * mk;
            }
        }
    }
    for (int o = 32; o > 0; o >>= 1) lsum += __shfl_down(lsum, o, 64);
    if (lane == 0) atomicAdd(&accumB[bid], lsum);   // per-block slot (no LDS left)
    __syncthreads();   // all 8 wave-atomics complete (vmcnt drained) before read
    if (tid == 0) {
        const float s0 = atomicAdd(&accumB[bid], 0.0f);   // read-back (returns old)
        atomicAdd(&accum[0], s0);
        __threadfence();
        const unsigned int prev = atomicAdd((unsigned int*)(accum + 2), 1u);
        if (prev == gridDim.x - 1) {   // last block finalizes
            const float s = atomicAdd(&accum[0], 0.0f);
            const float m = atomicAdd(&accum[1], 0.0f);
            out[0] = s / m;
        }
    }
}

extern "C" void kernel_launch(void* const* d_in, const int* in_sizes, int n_in,
                              void* d_out, int out_size, void* d_ws, size_t ws_size,
                              hipStream_t stream) {
    const float* ctx   = (const float*)d_in[0];
    const float* masks = (const float*)d_in[1];
    const float* ash   = (const float*)d_in[2];
    const float* ast   = (const float*)d_in[3];
    const float* sh    = (const float*)d_in[4];
    const float* st    = (const float*)d_in[5];
    const float* oh    = (const float*)d_in[6];
    const float* ot    = (const float*)d_in[7];
    const float* Ws_h  = (const float*)d_in[8];
    const float* bs_h  = (const float*)d_in[9];
    const float* Ws_t  = (const float*)d_in[10];
    const float* bs_t  = (const float*)d_in[11];
    const float* Wo_h  = (const float*)d_in[12];
    const float* bo_h  = (const float*)d_in[13];
    const float* Wo_t  = (const float*)d_in[14];
    const float* bo_t  = (const float*)d_in[15];
    float* out = (float*)d_out;

    char* ws = (char*)d_ws;
    float* accum   = (float*)(ws + 0);        // [0]=loss, [1]=msum, [2]=counter
    float* accumB  = (float*)(ws + 256);      // [256] per-block partials
    float* rowBias = (float*)(ws + 2048);     // [32][160] fp32
    unsigned short* WtG = (unsigned short*)(ws + 2048 + 32 * NPAD * 4); // [160][1024] bf16

    hipMemsetAsync(ws, 0, 1280, stream);      // accum + accumB
    aux_kernel<<<TBLK + B_, 256, 0, stream>>>(ctx, sh, st, masks, Wo_h, Wo_t,
                                              Ws_h, Ws_t, bo_h, bo_t, bs_h, bs_t,
                                              WtG, rowBias, accum);
    main_kernel<<<(M_ / MT) * 2, NTHR, 0, stream>>>(ctx, WtG, rowBias, masks,
                                                    ash, ast, oh, ot,
                                                    accum, accumB, out);
}